// Round 1
// baseline (916.802 us; speedup 1.0000x reference)
//
#include <hip/hip_runtime.h>
#include <math.h>

#define B_    4
#define S_    2048
#define BS_   8192       // B_*S_
#define DM_   1024
#define DS_   256
#define LB_   64
#define TOPK_ 8

// ---------------------------------------------------------------------------
// Generic tiled f32 GEMM: C[M,N] = epi(A[M,K] @ Bw[K,N] + bias[N])
// EPI: 0 = none
//      1 = tanh
//      2 = update: C[m,n] = extra0[m,n] + val * extra1[m]   (h += delta*gate)
//      3 = addx:   C[m,n] = extra0[m,n] + val               (out = x + proj)
// Tiles: BM=BN=64, BK=16, 256 threads (16x16), 4x4 per thread.
// ---------------------------------------------------------------------------
template<int EPI>
__global__ __launch_bounds__(256) void gemm_k(
    const float* __restrict__ A, const float* __restrict__ Bw,
    const float* __restrict__ bias, float* C,
    int M, int K, int N,
    const float* extra0, const float* extra1)
{
    __shared__ float As[16][65];
    __shared__ float Bs[16][65];
    const int tid = threadIdx.x;
    const int tx = tid & 15, ty = tid >> 4;
    const int bm = blockIdx.y * 64, bn = blockIdx.x * 64;

    float acc[4][4] = {};

    for (int k0 = 0; k0 < K; k0 += 16) {
        // A tile: 64 rows x 16 k   (1024 elems, 4 per thread)
        #pragma unroll
        for (int i = 0; i < 4; ++i) {
            int e = tid + i * 256;
            int r = e >> 4, kk = e & 15;
            As[kk][r] = A[(size_t)(bm + r) * K + (k0 + kk)];
        }
        // B tile: 16 k x 64 n
        #pragma unroll
        for (int i = 0; i < 4; ++i) {
            int e = tid + i * 256;
            int kk = e >> 6, n = e & 63;
            Bs[kk][n] = Bw[(size_t)(k0 + kk) * N + (bn + n)];
        }
        __syncthreads();
        #pragma unroll
        for (int kk = 0; kk < 16; ++kk) {
            float a[4], b[4];
            #pragma unroll
            for (int i = 0; i < 4; ++i) a[i] = As[kk][ty * 4 + i];
            #pragma unroll
            for (int j = 0; j < 4; ++j) b[j] = Bs[kk][tx * 4 + j];
            #pragma unroll
            for (int i = 0; i < 4; ++i)
                #pragma unroll
                for (int j = 0; j < 4; ++j)
                    acc[i][j] += a[i] * b[j];
        }
        __syncthreads();
    }

    #pragma unroll
    for (int i = 0; i < 4; ++i) {
        int m = bm + ty * 4 + i;
        #pragma unroll
        for (int j = 0; j < 4; ++j) {
            int n = bn + tx * 4 + j;
            float val = acc[i][j] + bias[n];
            if (EPI == 1) val = tanhf(val);
            else if (EPI == 2) val = extra0[(size_t)m * N + n] + val * extra1[m];
            else if (EPI == 3) val = extra0[(size_t)m * N + n] + val;
            C[(size_t)m * N + n] = val;
        }
    }
}

// ---------------------------------------------------------------------------
// ui-concat GEMM with tanh:  t = tanh([h|mixed|pb|summ] @ W1 + b1)
// K=1024 (4 segments of 256), M=8192, N=256. pb[m,:] = phproj[m>>4,:].
// ---------------------------------------------------------------------------
__global__ __launch_bounds__(256) void gemm_ui_k(
    const float* __restrict__ h, const float* __restrict__ mixed,
    const float* __restrict__ phproj, const float* __restrict__ summ,
    const float* __restrict__ W1, const float* __restrict__ b1,
    float* __restrict__ t)
{
    __shared__ float As[16][65];
    __shared__ float Bs[16][65];
    const int tid = threadIdx.x;
    const int tx = tid & 15, ty = tid >> 4;
    const int bm = blockIdx.y * 64, bn = blockIdx.x * 64;

    float acc[4][4] = {};

    for (int k0 = 0; k0 < 1024; k0 += 16) {
        const int seg = k0 >> 8;
        const int kbase = k0 & 255;
        const float* Asrc = (seg == 0) ? h : (seg == 1) ? mixed : (seg == 2) ? phproj : summ;
        const bool pool = (seg == 2);

        #pragma unroll
        for (int i = 0; i < 4; ++i) {
            int e = tid + i * 256;
            int r = e >> 4, kk = e & 15;
            int row = bm + r;
            if (pool) row >>= 4;
            As[kk][r] = Asrc[(size_t)row * DS_ + (kbase + kk)];
        }
        #pragma unroll
        for (int i = 0; i < 4; ++i) {
            int e = tid + i * 256;
            int kk = e >> 6, n = e & 63;
            Bs[kk][n] = W1[(size_t)(k0 + kk) * DS_ + (bn + n)];
        }
        __syncthreads();
        #pragma unroll
        for (int kk = 0; kk < 16; ++kk) {
            float a[4], b[4];
            #pragma unroll
            for (int i = 0; i < 4; ++i) a[i] = As[kk][ty * 4 + i];
            #pragma unroll
            for (int j = 0; j < 4; ++j) b[j] = Bs[kk][tx * 4 + j];
            #pragma unroll
            for (int i = 0; i < 4; ++i)
                #pragma unroll
                for (int j = 0; j < 4; ++j)
                    acc[i][j] += a[i] * b[j];
        }
        __syncthreads();
    }

    #pragma unroll
    for (int i = 0; i < 4; ++i) {
        int m = bm + ty * 4 + i;
        #pragma unroll
        for (int j = 0; j < 4; ++j) {
            int n = bn + tx * 4 + j;
            t[(size_t)m * DS_ + n] = tanhf(acc[i][j] + b1[n]);
        }
    }
}

// ---------------------------------------------------------------------------
// Causal depthwise conv (K=5) + chunk mean. One block per (b, chunk of 16).
// 256 threads, thread = channel d.
// ---------------------------------------------------------------------------
__global__ __launch_bounds__(256) void conv_pool_k(
    const float* __restrict__ h, const float* __restrict__ conv_w,
    const float* __restrict__ conv_b, float* __restrict__ mixed,
    float* __restrict__ cmean)
{
    const int blk = blockIdx.x;          // b*128 + c
    const int d = threadIdx.x;
    const int b = blk >> 7;
    const int s0 = (blk & 127) * 16;
    const float* hb = h + (size_t)b * S_ * DS_;
    float* mb = mixed + (size_t)b * S_ * DS_;

    const float w0 = conv_w[0 * DS_ + d], w1 = conv_w[1 * DS_ + d],
                w2 = conv_w[2 * DS_ + d], w3 = conv_w[3 * DS_ + d],
                w4 = conv_w[4 * DS_ + d];
    const float cb = conv_b[d];

    float a0 = (s0 >= 4) ? hb[(size_t)(s0 - 4) * DS_ + d] : 0.f;
    float a1 = (s0 >= 3) ? hb[(size_t)(s0 - 3) * DS_ + d] : 0.f;
    float a2 = (s0 >= 2) ? hb[(size_t)(s0 - 2) * DS_ + d] : 0.f;
    float a3 = (s0 >= 1) ? hb[(size_t)(s0 - 1) * DS_ + d] : 0.f;

    float sum = 0.f;
    #pragma unroll
    for (int tt = 0; tt < 16; ++tt) {
        int s = s0 + tt;
        float cur = hb[(size_t)s * DS_ + d];
        mb[(size_t)s * DS_ + d] = w0 * a0 + w1 * a1 + w2 * a2 + w3 * a3 + w4 * cur + cb;
        sum += cur;
        a0 = a1; a1 = a2; a2 = a3; a3 = cur;
    }
    cmean[(size_t)blk * DS_ + d] = sum * (1.f / 16.f);
}

// ---------------------------------------------------------------------------
// Halt gate: gate[m] = sigmoid(h[m,:]·Wh[:,2] + bh[2]). 4 tokens / block.
// ---------------------------------------------------------------------------
__global__ __launch_bounds__(256) void gate_k(
    const float* __restrict__ h, const float* __restrict__ Wh,
    const float* __restrict__ bh, float* __restrict__ gate)
{
    const int m = blockIdx.x * 4 + (threadIdx.x >> 6);
    const int lane = threadIdx.x & 63;
    const float* hr = h + (size_t)m * DS_;
    float p = 0.f;
    for (int j = lane; j < DS_; j += 64) p += hr[j] * Wh[j * 3 + 2];
    #pragma unroll
    for (int off = 32; off; off >>= 1) p += __shfl_down(p, off);
    if (lane == 0) gate[m] = 1.f / (1.f + expf(-(p + bh[2])));
}

// ---------------------------------------------------------------------------
// Windowed causal top-8 attention. One wave per token.
// lane l owns score for key token (s-64+l); butterfly argmax x8 (low-index
// tie-break = jax.lax.top_k stability); softmax over selected; weighted V sum.
// ---------------------------------------------------------------------------
__global__ __launch_bounds__(64) void attn_k(
    const float* __restrict__ q, const float* __restrict__ k,
    const float* __restrict__ v, float* __restrict__ summ)
{
    const int m = blockIdx.x;
    const int b = m >> 11;
    const int s = m & (S_ - 1);
    const int lane = threadIdx.x;

    const float4* q4 = reinterpret_cast<const float4*>(q + (size_t)m * DS_);
    const int row = s - LB_ + lane;

    float sc = -INFINITY;
    if (row >= 0) {
        const float4* k4 = reinterpret_cast<const float4*>(
            k + ((size_t)(b * S_) + row) * DS_);
        float acc = 0.f;
        #pragma unroll 8
        for (int j = 0; j < 64; ++j) {
            float4 a = q4[j], c = k4[j];
            acc += a.x * c.x + a.y * c.y + a.z * c.z + a.w * c.w;
        }
        sc = acc * 0.0625f;   // 1/sqrt(256)
    }

    float vals[TOPK_]; int idxs[TOPK_];
    #pragma unroll
    for (int t = 0; t < TOPK_; ++t) {
        float mv = sc; int mi = lane;
        #pragma unroll
        for (int off = 32; off; off >>= 1) {
            float ov = __shfl_xor(mv, off);
            int   oi = __shfl_xor(mi, off);
            if (ov > mv || (ov == mv && oi < mi)) { mv = ov; mi = oi; }
        }
        vals[t] = mv; idxs[t] = mi;
        if (lane == mi) sc = -INFINITY;
    }

    const float mref = (vals[0] == -INFINITY) ? 0.f : vals[0];
    float e[TOPK_], ssum = 0.f;
    #pragma unroll
    for (int t = 0; t < TOPK_; ++t) { e[t] = expf(vals[t] - mref); ssum += e[t]; }
    const float inv = 1.f / fmaxf(ssum, 1e-30f);

    float out[4] = {0.f, 0.f, 0.f, 0.f};
    #pragma unroll
    for (int t = 0; t < TOPK_; ++t) {
        float wt = e[t] * inv;
        int tok = s - LB_ + idxs[t];
        tok = min(max(tok, 0), S_ - 1);
        const float* vr = v + ((size_t)(b * S_) + tok) * DS_;
        #pragma unroll
        for (int i = 0; i < 4; ++i) out[i] += wt * vr[lane + i * 64];
    }
    #pragma unroll
    for (int i = 0; i < 4; ++i)
        summ[(size_t)m * DS_ + lane + i * 64] = out[i];
}

// ---------------------------------------------------------------------------
extern "C" void kernel_launch(void* const* d_in, const int* in_sizes, int n_in,
                              void* d_out, int out_size, void* d_ws, size_t ws_size,
                              hipStream_t stream)
{
    const float* x      = (const float*)d_in[0];
    const float* Wi     = (const float*)d_in[1];
    const float* bi     = (const float*)d_in[2];
    const float* conv_w = (const float*)d_in[3];
    const float* conv_b = (const float*)d_in[4];
    const float* Wp     = (const float*)d_in[5];
    const float* bp     = (const float*)d_in[6];
    const float* Wh     = (const float*)d_in[7];
    const float* bh     = (const float*)d_in[8];
    const float* Wq     = (const float*)d_in[9];
    const float* bq     = (const float*)d_in[10];
    const float* Wk     = (const float*)d_in[11];
    const float* bk     = (const float*)d_in[12];
    const float* Wv     = (const float*)d_in[13];
    const float* bv     = (const float*)d_in[14];
    const float* W1     = (const float*)d_in[15];
    const float* b1     = (const float*)d_in[16];
    const float* W2     = (const float*)d_in[17];
    const float* b2     = (const float*)d_in[18];
    const float* Wo     = (const float*)d_in[19];
    const float* bo     = (const float*)d_in[20];
    float* out = (float*)d_out;

    float* W     = (float*)d_ws;
    float* h     = W;                       // 8192*256
    float* mixed = h     + (size_t)BS_ * DS_;
    float* qb    = mixed + (size_t)BS_ * DS_;
    float* kb    = qb    + (size_t)BS_ * DS_;
    float* vb    = kb    + (size_t)BS_ * DS_;
    float* sm    = vb    + (size_t)BS_ * DS_;
    float* cmean = sm    + (size_t)BS_ * DS_;   // 512*256
    float* php   = cmean + (size_t)512 * DS_;   // 512*256
    float* gate  = php   + (size_t)512 * DS_;   // 8192
    float* tb    = qb;   // reuse q buffer after attention

    dim3 blk(256);
    dim3 g256(DS_ / 64, BS_ / 64);      // N=256 GEMMs on 8192 rows
    dim3 gpool(DS_ / 64, 512 / 64);     // pool projection
    dim3 gout(DM_ / 64, BS_ / 64);      // final N=1024

    // h = x @ Wi + bi
    gemm_k<0><<<g256, blk, 0, stream>>>(x, Wi, bi, h, BS_, DM_, DS_, nullptr, nullptr);

    for (int step = 0; step < 2; ++step) {
        conv_pool_k<<<512, blk, 0, stream>>>(h, conv_w, conv_b, mixed, cmean);
        gemm_k<0><<<gpool, blk, 0, stream>>>(cmean, Wp, bp, php, 512, DS_, DS_, nullptr, nullptr);
        gemm_k<0><<<g256, blk, 0, stream>>>(h, Wq, bq, qb, BS_, DS_, DS_, nullptr, nullptr);
        gemm_k<0><<<g256, blk, 0, stream>>>(h, Wk, bk, kb, BS_, DS_, DS_, nullptr, nullptr);
        gemm_k<0><<<g256, blk, 0, stream>>>(h, Wv, bv, vb, BS_, DS_, DS_, nullptr, nullptr);
        gate_k<<<BS_ / 4, blk, 0, stream>>>(h, Wh, bh, gate);
        attn_k<<<BS_, dim3(64), 0, stream>>>(qb, kb, vb, sm);
        gemm_ui_k<<<g256, blk, 0, stream>>>(h, mixed, php, sm, W1, b1, tb);
        // h = h + (tanh(ui@W1+b1) @ W2 + b2) * gate
        gemm_k<2><<<g256, blk, 0, stream>>>(tb, W2, b2, h, BS_, DS_, DS_, h, gate);
    }

    // out = x + h @ Wo + bo
    gemm_k<3><<<gout, blk, 0, stream>>>(h, Wo, bo, out, BS_, DS_, DM_, x, nullptr);
}

// Round 2
// 361.386 us; speedup vs baseline: 2.5369x; 2.5369x over previous
//
#include <hip/hip_runtime.h>
#include <math.h>

#define B_    4
#define S_    2048
#define BS_   8192       // B_*S_
#define DM_   1024
#define DS_   256
#define LB_   64
#define TOPK_ 8

typedef __bf16 bf16x8 __attribute__((ext_vector_type(8)));
typedef float  f32x4  __attribute__((ext_vector_type(4)));

static __device__ __forceinline__ unsigned short f2bf(float f) {
    union { float f; unsigned u; } a; a.f = f;
    unsigned u = a.u;
    unsigned r = u + 0x7FFFu + ((u >> 16) & 1u);   // RNE
    return (unsigned short)(r >> 16);
}
static __device__ __forceinline__ unsigned pack2(float a, float b) {
    return (unsigned)f2bf(a) | ((unsigned)f2bf(b) << 16);
}
// granule swizzle: 16B granule index within a 64B row
static __device__ __forceinline__ int swz(int row, int cb) {
    return (cb ^ (row & 3) ^ ((row >> 2) & 3)) & 3;
}

// ---------------------------------------------------------------------------
// MFMA bf16 GEMM: C[M,N] = epi(A_f32[M,K] @ Bt_bf16[N,K]^T + bias[N])
// Tile 128x64, BK=32, 256 threads = 4 waves (2x2), wave tile 64x32,
// fragments 4(M) x 2(N) of 16x16x32.
// EPI: 0 none | 2 h-update: C=extra0+val*extra1[m] | 3 addx: C=extra0+val
// ---------------------------------------------------------------------------
template<int EPI>
__global__ __launch_bounds__(256) void mm_k(
    const float* __restrict__ A, const unsigned short* __restrict__ Bt,
    const float* __restrict__ bias, float* __restrict__ C,
    int M, int K, int N,
    const float* __restrict__ extra0, const float* __restrict__ extra1)
{
    __shared__ unsigned char smem[12288];   // A: 128*64B, B: 64*64B
    unsigned char* smA = smem;
    unsigned char* smB = smem + 8192;

    const int tid  = threadIdx.x;
    const int lane = tid & 63;
    const int wid  = tid >> 6;
    const int wm   = wid >> 1, wn = wid & 1;
    const int bm   = blockIdx.y * 128, bn = blockIdx.x * 64;
    const int lr   = lane & 15, lc = lane >> 4;

    f32x4 acc[4][2] = {};

    for (int k0 = 0; k0 < K; k0 += 32) {
        // stage A: 512 granules (128 rows x 4 cb), 2 per thread
        #pragma unroll
        for (int i = 0; i < 2; ++i) {
            int e = tid + i * 256;
            int row = e >> 2, cb = e & 3;
            const float* src = A + (size_t)(bm + row) * K + k0 + cb * 8;
            float4 u = *reinterpret_cast<const float4*>(src);
            float4 w = *reinterpret_cast<const float4*>(src + 4);
            uint4 g;
            g.x = pack2(u.x, u.y); g.y = pack2(u.z, u.w);
            g.z = pack2(w.x, w.y); g.w = pack2(w.z, w.w);
            *reinterpret_cast<uint4*>(smA + row * 64 + swz(row, cb) * 16) = g;
        }
        // stage B: 256 granules (64 rows x 4 cb), 1 per thread
        {
            int row = tid >> 2, cb = tid & 3;
            uint4 g = *reinterpret_cast<const uint4*>(
                Bt + (size_t)(bn + row) * K + k0 + cb * 8);
            *reinterpret_cast<uint4*>(smB + row * 64 + swz(row, cb) * 16) = g;
        }
        __syncthreads();

        bf16x8 af[4], bfr[2];
        #pragma unroll
        for (int i = 0; i < 4; ++i) {
            int m = wm * 64 + i * 16 + lr;
            af[i] = *reinterpret_cast<const bf16x8*>(smA + m * 64 + swz(m, lc) * 16);
        }
        #pragma unroll
        for (int j = 0; j < 2; ++j) {
            int n = wn * 32 + j * 16 + lr;
            bfr[j] = *reinterpret_cast<const bf16x8*>(smB + n * 64 + swz(n, lc) * 16);
        }
        #pragma unroll
        for (int i = 0; i < 4; ++i)
            #pragma unroll
            for (int j = 0; j < 2; ++j)
                acc[i][j] = __builtin_amdgcn_mfma_f32_16x16x32_bf16(
                    af[i], bfr[j], acc[i][j], 0, 0, 0);
        __syncthreads();
    }

    #pragma unroll
    for (int i = 0; i < 4; ++i) {
        #pragma unroll
        for (int j = 0; j < 2; ++j) {
            int col = bn + wn * 32 + j * 16 + lr;
            #pragma unroll
            for (int r = 0; r < 4; ++r) {
                int row = bm + wm * 64 + i * 16 + lc * 4 + r;
                float val = acc[i][j][r] + bias[col];
                if (EPI == 2)      val = extra0[(size_t)row * N + col] + val * extra1[row];
                else if (EPI == 3) val = extra0[(size_t)row * N + col] + val;
                C[(size_t)row * N + col] = val;
            }
        }
    }
}

// ---------------------------------------------------------------------------
// ui-concat MFMA GEMM + tanh: t = tanh([h|mixed|pb|summ] @ W1 + b1)
// K=1024 (4 segments of 256), pb[m,:] = php[m>>4,:]. N=256, M=8192.
// ---------------------------------------------------------------------------
__global__ __launch_bounds__(256) void mm_ui_k(
    const float* __restrict__ h, const float* __restrict__ mixed,
    const float* __restrict__ php, const float* __restrict__ summ,
    const unsigned short* __restrict__ W1t, const float* __restrict__ b1,
    float* __restrict__ t)
{
    __shared__ unsigned char smem[12288];
    unsigned char* smA = smem;
    unsigned char* smB = smem + 8192;

    const int tid  = threadIdx.x;
    const int lane = tid & 63;
    const int wid  = tid >> 6;
    const int wm   = wid >> 1, wn = wid & 1;
    const int bm   = blockIdx.y * 128, bn = blockIdx.x * 64;
    const int lr   = lane & 15, lc = lane >> 4;

    f32x4 acc[4][2] = {};

    for (int k0 = 0; k0 < 1024; k0 += 32) {
        const int seg = k0 >> 8, kb = k0 & 255;
        const float* Asrc = (seg == 0) ? h : (seg == 1) ? mixed : (seg == 2) ? php : summ;
        #pragma unroll
        for (int i = 0; i < 2; ++i) {
            int e = tid + i * 256;
            int row = e >> 2, cb = e & 3;
            int rs = bm + row;
            if (seg == 2) rs >>= 4;
            const float* src = Asrc + (size_t)rs * DS_ + kb + cb * 8;
            float4 u = *reinterpret_cast<const float4*>(src);
            float4 w = *reinterpret_cast<const float4*>(src + 4);
            uint4 g;
            g.x = pack2(u.x, u.y); g.y = pack2(u.z, u.w);
            g.z = pack2(w.x, w.y); g.w = pack2(w.z, w.w);
            *reinterpret_cast<uint4*>(smA + row * 64 + swz(row, cb) * 16) = g;
        }
        {
            int row = tid >> 2, cb = tid & 3;
            uint4 g = *reinterpret_cast<const uint4*>(
                W1t + (size_t)(bn + row) * 1024 + k0 + cb * 8);
            *reinterpret_cast<uint4*>(smB + row * 64 + swz(row, cb) * 16) = g;
        }
        __syncthreads();

        bf16x8 af[4], bfr[2];
        #pragma unroll
        for (int i = 0; i < 4; ++i) {
            int m = wm * 64 + i * 16 + lr;
            af[i] = *reinterpret_cast<const bf16x8*>(smA + m * 64 + swz(m, lc) * 16);
        }
        #pragma unroll
        for (int j = 0; j < 2; ++j) {
            int n = wn * 32 + j * 16 + lr;
            bfr[j] = *reinterpret_cast<const bf16x8*>(smB + n * 64 + swz(n, lc) * 16);
        }
        #pragma unroll
        for (int i = 0; i < 4; ++i)
            #pragma unroll
            for (int j = 0; j < 2; ++j)
                acc[i][j] = __builtin_amdgcn_mfma_f32_16x16x32_bf16(
                    af[i], bfr[j], acc[i][j], 0, 0, 0);
        __syncthreads();
    }

    #pragma unroll
    for (int i = 0; i < 4; ++i) {
        #pragma unroll
        for (int j = 0; j < 2; ++j) {
            int col = bn + wn * 32 + j * 16 + lr;
            #pragma unroll
            for (int r = 0; r < 4; ++r) {
                int row = bm + wm * 64 + i * 16 + lc * 4 + r;
                t[(size_t)row * DS_ + col] = tanhf(acc[i][j][r] + b1[col]);
            }
        }
    }
}

// ---------------------------------------------------------------------------
// Weight prep: out_bf16[N][K] = bf16(in_f32[K][N])  (32x32 LDS tile transpose)
// ---------------------------------------------------------------------------
__global__ __launch_bounds__(256) void transpose_cvt_k(
    const float* __restrict__ in, unsigned short* __restrict__ out, int K, int N)
{
    __shared__ float t[32][33];
    const int k0 = blockIdx.y * 32, n0 = blockIdx.x * 32;
    const int tx = threadIdx.x & 31, ty = threadIdx.x >> 5;
    #pragma unroll
    for (int r = 0; r < 32; r += 8)
        t[ty + r][tx] = in[(size_t)(k0 + ty + r) * N + n0 + tx];
    __syncthreads();
    #pragma unroll
    for (int r = 0; r < 32; r += 8)
        out[(size_t)(n0 + ty + r) * K + k0 + tx] = f2bf(t[tx][ty + r]);
}

__global__ __launch_bounds__(256) void biascat_k(
    const float* __restrict__ bq, const float* __restrict__ bk,
    const float* __restrict__ bv, float* __restrict__ bqkv)
{
    int i = blockIdx.x * 256 + threadIdx.x;
    if (i < 768) {
        float v = (i < 256) ? bq[i] : (i < 512) ? bk[i - 256] : bv[i - 512];
        bqkv[i] = v;
    }
}

// ---------------------------------------------------------------------------
// Causal depthwise conv (K=5) + chunk mean. One block per (b, chunk of 16).
// ---------------------------------------------------------------------------
__global__ __launch_bounds__(256) void conv_pool_k(
    const float* __restrict__ h, const float* __restrict__ conv_w,
    const float* __restrict__ conv_b, float* __restrict__ mixed,
    float* __restrict__ cmean)
{
    const int blk = blockIdx.x;          // b*128 + c
    const int d = threadIdx.x;
    const int b = blk >> 7;
    const int s0 = (blk & 127) * 16;
    const float* hb = h + (size_t)b * S_ * DS_;
    float* mb = mixed + (size_t)b * S_ * DS_;

    const float w0 = conv_w[0 * DS_ + d], w1 = conv_w[1 * DS_ + d],
                w2 = conv_w[2 * DS_ + d], w3 = conv_w[3 * DS_ + d],
                w4 = conv_w[4 * DS_ + d];
    const float cb = conv_b[d];

    float a0 = (s0 >= 4) ? hb[(size_t)(s0 - 4) * DS_ + d] : 0.f;
    float a1 = (s0 >= 3) ? hb[(size_t)(s0 - 3) * DS_ + d] : 0.f;
    float a2 = (s0 >= 2) ? hb[(size_t)(s0 - 2) * DS_ + d] : 0.f;
    float a3 = (s0 >= 1) ? hb[(size_t)(s0 - 1) * DS_ + d] : 0.f;

    float sum = 0.f;
    #pragma unroll
    for (int tt = 0; tt < 16; ++tt) {
        int s = s0 + tt;
        float cur = hb[(size_t)s * DS_ + d];
        mb[(size_t)s * DS_ + d] = w0 * a0 + w1 * a1 + w2 * a2 + w3 * a3 + w4 * cur + cb;
        sum += cur;
        a0 = a1; a1 = a2; a2 = a3; a3 = cur;
    }
    cmean[(size_t)blk * DS_ + d] = sum * (1.f / 16.f);
}

// ---------------------------------------------------------------------------
// Halt gate: gate[m] = sigmoid(h[m,:]·Wh[:,2] + bh[2]). 4 tokens / block.
// ---------------------------------------------------------------------------
__global__ __launch_bounds__(256) void gate_k(
    const float* __restrict__ h, const float* __restrict__ Wh,
    const float* __restrict__ bh, float* __restrict__ gate)
{
    const int m = blockIdx.x * 4 + (threadIdx.x >> 6);
    const int lane = threadIdx.x & 63;
    const float* hr = h + (size_t)m * DS_;
    float p = 0.f;
    for (int j = lane; j < DS_; j += 64) p += hr[j] * Wh[j * 3 + 2];
    #pragma unroll
    for (int off = 32; off; off >>= 1) p += __shfl_down(p, off);
    if (lane == 0) gate[m] = 1.f / (1.f + expf(-(p + bh[2])));
}

// ---------------------------------------------------------------------------
// Windowed causal top-8 attention, reading fused qkv[M][768].
// One wave per token; butterfly argmax x8 with low-index tie-break.
// ---------------------------------------------------------------------------
__global__ __launch_bounds__(64) void attn_k(
    const float* __restrict__ qkv, float* __restrict__ summ)
{
    const int m = blockIdx.x;
    const int b = m >> 11;
    const int s = m & (S_ - 1);
    const int lane = threadIdx.x;

    const float4* q4 = reinterpret_cast<const float4*>(qkv + (size_t)m * 768);
    const int row = s - LB_ + lane;

    float sc = -INFINITY;
    if (row >= 0) {
        const float4* k4 = reinterpret_cast<const float4*>(
            qkv + ((size_t)(b * S_) + row) * 768 + 256);
        float acc = 0.f;
        #pragma unroll 8
        for (int j = 0; j < 64; ++j) {
            float4 a = q4[j], c = k4[j];
            acc += a.x * c.x + a.y * c.y + a.z * c.z + a.w * c.w;
        }
        sc = acc * 0.0625f;   // 1/sqrt(256)
    }

    float vals[TOPK_]; int idxs[TOPK_];
    #pragma unroll
    for (int t = 0; t < TOPK_; ++t) {
        float mv = sc; int mi = lane;
        #pragma unroll
        for (int off = 32; off; off >>= 1) {
            float ov = __shfl_xor(mv, off);
            int   oi = __shfl_xor(mi, off);
            if (ov > mv || (ov == mv && oi < mi)) { mv = ov; mi = oi; }
        }
        vals[t] = mv; idxs[t] = mi;
        if (lane == mi) sc = -INFINITY;
    }

    const float mref = (vals[0] == -INFINITY) ? 0.f : vals[0];
    float e[TOPK_], ssum = 0.f;
    #pragma unroll
    for (int t = 0; t < TOPK_; ++t) { e[t] = expf(vals[t] - mref); ssum += e[t]; }
    const float inv = 1.f / fmaxf(ssum, 1e-30f);

    float out[4] = {0.f, 0.f, 0.f, 0.f};
    #pragma unroll
    for (int t = 0; t < TOPK_; ++t) {
        float wt = e[t] * inv;
        int tok = s - LB_ + idxs[t];
        tok = min(max(tok, 0), S_ - 1);
        const float* vr = qkv + ((size_t)(b * S_) + tok) * 768 + 512;
        #pragma unroll
        for (int i = 0; i < 4; ++i) out[i] += wt * vr[lane + i * 64];
    }
    #pragma unroll
    for (int i = 0; i < 4; ++i)
        summ[(size_t)m * DS_ + lane + i * 64] = out[i];
}

// ---------------------------------------------------------------------------
extern "C" void kernel_launch(void* const* d_in, const int* in_sizes, int n_in,
                              void* d_out, int out_size, void* d_ws, size_t ws_size,
                              hipStream_t stream)
{
    const float* x      = (const float*)d_in[0];
    const float* Wi     = (const float*)d_in[1];
    const float* bi     = (const float*)d_in[2];
    const float* conv_w = (const float*)d_in[3];
    const float* conv_b = (const float*)d_in[4];
    const float* Wp     = (const float*)d_in[5];
    const float* bp     = (const float*)d_in[6];
    const float* Wh     = (const float*)d_in[7];
    const float* bh     = (const float*)d_in[8];
    const float* Wq     = (const float*)d_in[9];
    const float* bq     = (const float*)d_in[10];
    const float* Wk     = (const float*)d_in[11];
    const float* bk     = (const float*)d_in[12];
    const float* Wv     = (const float*)d_in[13];
    const float* bv     = (const float*)d_in[14];
    const float* W1     = (const float*)d_in[15];
    const float* b1     = (const float*)d_in[16];
    const float* W2     = (const float*)d_in[17];
    const float* b2     = (const float*)d_in[18];
    const float* Wo     = (const float*)d_in[19];
    const float* bo     = (const float*)d_in[20];
    float* out = (float*)d_out;

    float* F     = (float*)d_ws;
    float* h     = F;                            // 8192*256
    float* mixed = h     + (size_t)BS_ * DS_;    // 8192*256
    float* qkv   = mixed + (size_t)BS_ * DS_;    // 8192*768
    float* sm    = qkv   + (size_t)BS_ * 768;    // 8192*256
    float* tb    = sm    + (size_t)BS_ * DS_;    // 8192*256
    float* cmean = tb    + (size_t)BS_ * DS_;    // 512*256
    float* php   = cmean + (size_t)512 * DS_;    // 512*256
    float* gate  = php   + (size_t)512 * DS_;    // 8192
    float* bqkv  = gate  + BS_;                  // 768
    unsigned short* U = (unsigned short*)(bqkv + 768);
    unsigned short* Wit   = U;                         // 256 x 1024
    unsigned short* Wqkvt = Wit   + (size_t)256 * 1024; // 768 x 256
    unsigned short* Wpt   = Wqkvt + (size_t)768 * 256;  // 256 x 256
    unsigned short* W1t   = Wpt   + (size_t)256 * 256;  // 256 x 1024
    unsigned short* W2t   = W1t   + (size_t)256 * 1024; // 256 x 256
    unsigned short* Wot   = W2t   + (size_t)256 * 256;  // 1024 x 256

    dim3 blk(256);

    // ---- weight prep (runs every call; ~10 us total) ----
    transpose_cvt_k<<<dim3(256 / 32, 1024 / 32), blk, 0, stream>>>(Wi, Wit, 1024, 256);
    transpose_cvt_k<<<dim3(256 / 32, 256 / 32),  blk, 0, stream>>>(Wq, Wqkvt,              256, 256);
    transpose_cvt_k<<<dim3(256 / 32, 256 / 32),  blk, 0, stream>>>(Wk, Wqkvt + 256 * 256,  256, 256);
    transpose_cvt_k<<<dim3(256 / 32, 256 / 32),  blk, 0, stream>>>(Wv, Wqkvt + 512 * 256,  256, 256);
    transpose_cvt_k<<<dim3(256 / 32, 256 / 32),  blk, 0, stream>>>(Wp, Wpt, 256, 256);
    transpose_cvt_k<<<dim3(256 / 32, 1024 / 32), blk, 0, stream>>>(W1, W1t, 1024, 256);
    transpose_cvt_k<<<dim3(256 / 32, 256 / 32),  blk, 0, stream>>>(W2, W2t, 256, 256);
    transpose_cvt_k<<<dim3(1024 / 32, 256 / 32), blk, 0, stream>>>(Wo, Wot, 256, 1024);
    biascat_k<<<3, blk, 0, stream>>>(bq, bk, bv, bqkv);

    // ---- forward ----
    // h = x @ Wi + bi
    mm_k<0><<<dim3(4, 64), blk, 0, stream>>>(x, Wit, bi, h, BS_, DM_, DS_, nullptr, nullptr);

    for (int step = 0; step < 2; ++step) {
        conv_pool_k<<<512, blk, 0, stream>>>(h, conv_w, conv_b, mixed, cmean);
        mm_k<0><<<dim3(4, 4), blk, 0, stream>>>(cmean, Wpt, bp, php, 512, DS_, DS_, nullptr, nullptr);
        mm_k<0><<<dim3(12, 64), blk, 0, stream>>>(h, Wqkvt, bqkv, qkv, BS_, DS_, 768, nullptr, nullptr);
        gate_k<<<BS_ / 4, blk, 0, stream>>>(h, Wh, bh, gate);
        attn_k<<<BS_, dim3(64), 0, stream>>>(qkv, sm);
        mm_ui_k<<<dim3(4, 64), blk, 0, stream>>>(h, mixed, php, sm, W1t, b1, tb);
        // h = h + (tanh(ui@W1+b1) @ W2 + b2) * gate
        mm_k<2><<<dim3(4, 64), blk, 0, stream>>>(tb, W2t, b2, h, BS_, DS_, DS_, h, gate);
    }

    // out = x + h @ Wo + bo
    mm_k<3><<<dim3(16, 64), blk, 0, stream>>>(h, Wot, bo, out, BS_, DS_, DM_, x, nullptr);
}